// Round 1
// baseline (3332.033 us; speedup 1.0000x reference)
//
#include <hip/hip_runtime.h>
#include <hip/hip_bf16.h>

#define N_NODES   50000
#define N_EDGES   600000
#define N_GRAPHS  500
#define IN_DIM    64
#define D         128
#define N_CLASSES 10
#define N_PROTO   50
#define GRAPH_SZ  10
#define EPS_F     1e-4f

// ---------------- degree / norm ----------------
__global__ void k_init_deg(float* deg) {
    int i = blockIdx.x * blockDim.x + threadIdx.x;
    if (i < N_NODES) deg[i] = 1.0f;
}

__global__ void k_count_deg(const int* __restrict__ dst, float* deg) {
    int e = blockIdx.x * blockDim.x + threadIdx.x;
    if (e < N_EDGES) atomicAdd(&deg[dst[e]], 1.0f);
}

__global__ void k_rsqrt(float* deg) {
    int i = blockIdx.x * blockDim.x + threadIdx.x;
    if (i < N_NODES) deg[i] = rsqrtf(deg[i]);   // deg buffer becomes dis
}

__global__ void k_edge_norm(const int* __restrict__ src, const int* __restrict__ dst,
                            const float* __restrict__ dis, float* __restrict__ norm) {
    int e = blockIdx.x * blockDim.x + threadIdx.x;
    if (e < N_EDGES) norm[e] = dis[src[e]] * dis[dst[e]];
}

// ---------------- dense GEMM: out[N, 128] = in[N, DIN] @ W[DIN, 128] ----------------
// 128 threads per block (one col each), 4 rows per block; W element reused 4x in regs.
template <int DIN>
__global__ void k_gemm(const float* __restrict__ in, const float* __restrict__ W,
                       float* __restrict__ out) {
    int col  = threadIdx.x;          // 0..127
    int row0 = blockIdx.x * 4;
    const float* r = in + (size_t)row0 * DIN;
    float a0 = 0.f, a1 = 0.f, a2 = 0.f, a3 = 0.f;
#pragma unroll 8
    for (int k = 0; k < DIN; ++k) {
        float w = W[k * D + col];
        a0 = fmaf(r[k],           w, a0);
        a1 = fmaf(r[DIN + k],     w, a1);
        a2 = fmaf(r[2 * DIN + k], w, a2);
        a3 = fmaf(r[3 * DIN + k], w, a3);
    }
    size_t o = (size_t)row0 * D + col;
    out[o] = a0; out[o + D] = a1; out[o + 2 * D] = a2; out[o + 3 * D] = a3;
}

// ---------------- edge scatter: agg[dst] += hw[src] * norm ----------------
// 32 threads per edge, float4 per thread (4 features), atomic adds.
__global__ void k_scatter(const int* __restrict__ src, const int* __restrict__ dst,
                          const float* __restrict__ norm, const float* __restrict__ hw,
                          float* __restrict__ agg) {
    long long t = (long long)blockIdx.x * blockDim.x + threadIdx.x;
    int e = (int)(t >> 5);
    if (e >= N_EDGES) return;
    int j4 = ((int)t & 31) * 4;
    int s = src[e], d = dst[e];
    float nm = norm[e];
    const float4 v = *(const float4*)&hw[(size_t)s * D + j4];
    float* a = &agg[(size_t)d * D + j4];
    atomicAdd(a + 0, v.x * nm);
    atomicAdd(a + 1, v.y * nm);
    atomicAdd(a + 2, v.z * nm);
    atomicAdd(a + 3, v.w * nm);
}

// ---------------- self-loop + bias + relu ----------------
__global__ void k_selfloop_relu(const float* __restrict__ hw, const float* __restrict__ dis,
                                const float* __restrict__ b, float* __restrict__ agg) {
    long long i = (long long)blockIdx.x * blockDim.x + threadIdx.x;
    if (i >= (long long)N_NODES * D) return;
    int n = (int)(i >> 7), j = (int)(i & 127);
    float dd = dis[n];
    float v = agg[i] + hw[i] * dd * dd + b[j];
    agg[i] = fmaxf(v, 0.0f);
}

// ---------------- readout ----------------
__global__ void k_counts(const int* __restrict__ batch, float* counts) {
    int n = blockIdx.x * blockDim.x + threadIdx.x;
    if (n < N_NODES) atomicAdd(&counts[batch[n]], 1.0f);
}

__global__ void k_gsum(const int* __restrict__ batch, const float* __restrict__ h,
                       float* __restrict__ gsum) {
    long long i = (long long)blockIdx.x * blockDim.x + threadIdx.x;
    if (i >= (long long)N_NODES * D) return;
    int n = (int)(i >> 7), j = (int)(i & 127);
    atomicAdd(&gsum[(size_t)batch[n] * D + j], h[i]);
}

__global__ void k_gdiv(float* gsum, const float* __restrict__ counts) {
    int i = blockIdx.x * blockDim.x + threadIdx.x;
    if (i >= N_GRAPHS * D) return;
    gsum[i] /= fmaxf(counts[i >> 7], 1.0f);
}

// ---------------- prototypes / distances / logits ----------------
__global__ void k_proto(const float* __restrict__ pe, float* __restrict__ pg) {
    int i = blockIdx.x * blockDim.x + threadIdx.x;   // N_PROTO * D = 6400
    if (i >= N_PROTO * D) return;
    int p = i >> 7, j = i & 127;
    float s = 0.f;
#pragma unroll
    for (int g = 0; g < GRAPH_SZ; ++g) s += pe[((size_t)p * GRAPH_SZ + g) * D + j];
    pg[i] = s * (1.0f / GRAPH_SZ);
}

__global__ void k_sim(const float* __restrict__ ge, const float* __restrict__ pg,
                      float* __restrict__ sim) {
    int t = blockIdx.x * blockDim.x + threadIdx.x;   // N_GRAPHS * N_PROTO = 25000
    if (t >= N_GRAPHS * N_PROTO) return;
    int b = t / N_PROTO, p = t % N_PROTO;
    const float* g = ge + (size_t)b * D;
    const float* q = pg + (size_t)p * D;
    float d2 = 0.f;
#pragma unroll 8
    for (int j = 0; j < D; ++j) { float df = g[j] - q[j]; d2 = fmaf(df, df, d2); }
    sim[t] = logf((d2 + 1.0f) / (d2 + EPS_F));
}

__global__ void k_logits(const float* __restrict__ sim, const float* __restrict__ lw,
                         float* __restrict__ out) {
    int t = blockIdx.x * blockDim.x + threadIdx.x;   // N_GRAPHS * N_CLASSES = 5000
    if (t >= N_GRAPHS * N_CLASSES) return;
    int b = t / N_CLASSES, c = t % N_CLASSES;
    float s = 0.f;
#pragma unroll
    for (int p = 0; p < N_PROTO; ++p) s = fmaf(sim[b * N_PROTO + p], lw[c * N_PROTO + p], s);
    out[t] = s;
}

extern "C" void kernel_launch(void* const* d_in, const int* in_sizes, int n_in,
                              void* d_out, int out_size, void* d_ws, size_t ws_size,
                              hipStream_t stream) {
    const float* x   = (const float*)d_in[0];
    const int*   ei  = (const int*)d_in[1];      // [2, E] flat: src row, then dst row
    const int*   bat = (const int*)d_in[2];
    const float* W0  = (const float*)d_in[3];
    const float* b0  = (const float*)d_in[4];
    const float* W1  = (const float*)d_in[5];
    const float* b1  = (const float*)d_in[6];
    const float* W2  = (const float*)d_in[7];
    const float* b2  = (const float*)d_in[8];
    const float* pe  = (const float*)d_in[9];
    const float* lw  = (const float*)d_in[10];
    float* out = (float*)d_out;

    const int* esrc = ei;
    const int* edst = ei + N_EDGES;

    float* ws   = (float*)d_ws;
    float* buf1 = ws;                         // N*D
    float* buf2 = buf1 + (size_t)N_NODES * D; // N*D
    float* dis  = buf2 + (size_t)N_NODES * D; // N
    float* norm = dis + N_NODES;              // E
    float* cnts = norm + N_EDGES;             // N_GRAPHS
    float* gsum = cnts + N_GRAPHS;            // N_GRAPHS*D
    float* pg   = gsum + (size_t)N_GRAPHS * D;// N_PROTO*D
    float* sim  = pg + N_PROTO * D;           // N_GRAPHS*N_PROTO

    const int TB = 256;
    const size_t ND = (size_t)N_NODES * D;
    int nd_blocks = (int)((ND + TB - 1) / TB);
    int e_blocks  = (N_EDGES + TB - 1) / TB;
    int n_blocks  = (N_NODES + TB - 1) / TB;

    // degrees & edge norms
    k_init_deg<<<n_blocks, TB, 0, stream>>>(dis);
    k_count_deg<<<e_blocks, TB, 0, stream>>>(edst, dis);
    k_rsqrt<<<n_blocks, TB, 0, stream>>>(dis);
    k_edge_norm<<<e_blocks, TB, 0, stream>>>(esrc, edst, dis, norm);

    long long sc_threads = (long long)N_EDGES * 32;
    int sc_blocks = (int)((sc_threads + TB - 1) / TB);

    // ---- layer 0: x[N,64] -> h1 in buf2 ----
    k_gemm<IN_DIM><<<N_NODES / 4, 128, 0, stream>>>(x, W0, buf1);
    hipMemsetAsync(buf2, 0, ND * sizeof(float), stream);
    k_scatter<<<sc_blocks, TB, 0, stream>>>(esrc, edst, norm, buf1, buf2);
    k_selfloop_relu<<<nd_blocks, TB, 0, stream>>>(buf1, dis, b0, buf2);

    // ---- layer 1 ----
    k_gemm<D><<<N_NODES / 4, 128, 0, stream>>>(buf2, W1, buf1);
    hipMemsetAsync(buf2, 0, ND * sizeof(float), stream);
    k_scatter<<<sc_blocks, TB, 0, stream>>>(esrc, edst, norm, buf1, buf2);
    k_selfloop_relu<<<nd_blocks, TB, 0, stream>>>(buf1, dis, b1, buf2);

    // ---- layer 2 ----
    k_gemm<D><<<N_NODES / 4, 128, 0, stream>>>(buf2, W2, buf1);
    hipMemsetAsync(buf2, 0, ND * sizeof(float), stream);
    k_scatter<<<sc_blocks, TB, 0, stream>>>(esrc, edst, norm, buf1, buf2);
    k_selfloop_relu<<<nd_blocks, TB, 0, stream>>>(buf1, dis, b2, buf2);

    // ---- readout ----
    hipMemsetAsync(cnts, 0, N_GRAPHS * sizeof(float), stream);
    hipMemsetAsync(gsum, 0, (size_t)N_GRAPHS * D * sizeof(float), stream);
    k_counts<<<n_blocks, TB, 0, stream>>>(bat, cnts);
    k_gsum<<<nd_blocks, TB, 0, stream>>>(bat, buf2, gsum);
    k_gdiv<<<(N_GRAPHS * D + TB - 1) / TB, TB, 0, stream>>>(gsum, cnts);

    // ---- prototypes, similarities, logits ----
    k_proto<<<(N_PROTO * D + TB - 1) / TB, TB, 0, stream>>>(pe, pg);
    k_sim<<<(N_GRAPHS * N_PROTO + TB - 1) / TB, TB, 0, stream>>>(gsum, pg, sim);
    k_logits<<<(N_GRAPHS * N_CLASSES + TB - 1) / TB, TB, 0, stream>>>(sim, lw, out);
}

// Round 2
// 427.185 us; speedup vs baseline: 7.8000x; 7.8000x over previous
//
#include <hip/hip_runtime.h>
#include <hip/hip_bf16.h>

#define N_NODES   50000
#define N_EDGES   600000
#define N_GRAPHS  500
#define IN_DIM    64
#define D         128
#define N_CLASSES 10
#define N_PROTO   50
#define GRAPH_SZ  10
#define EPS_F     1e-4f
#define SCAN_B    256

// ---------------- degree ----------------
__global__ void k_count_indeg(const int* __restrict__ dst, int* __restrict__ indeg) {
    int e = blockIdx.x * blockDim.x + threadIdx.x;
    if (e < N_EDGES) atomicAdd(&indeg[dst[e]], 1);
}

__global__ void k_dis(const int* __restrict__ indeg, float* __restrict__ dis) {
    int i = blockIdx.x * blockDim.x + threadIdx.x;
    if (i < N_NODES) dis[i] = rsqrtf(1.0f + (float)indeg[i]);
}

// ---------------- exclusive scan (2-level) ----------------
__global__ void k_scan1(const int* __restrict__ in, int* __restrict__ out,
                        int* __restrict__ bsum, int n) {
    __shared__ int tmp[SCAN_B];
    int i = blockIdx.x * SCAN_B + threadIdx.x;
    int v = (i < n) ? in[i] : 0;
    tmp[threadIdx.x] = v;
    __syncthreads();
    for (int off = 1; off < SCAN_B; off <<= 1) {
        int t = (threadIdx.x >= off) ? tmp[threadIdx.x - off] : 0;
        __syncthreads();
        tmp[threadIdx.x] += t;
        __syncthreads();
    }
    if (i < n) out[i] = tmp[threadIdx.x] - v;          // exclusive
    if (threadIdx.x == SCAN_B - 1) bsum[blockIdx.x] = tmp[threadIdx.x];
}

__global__ void k_scan2(int* bsum, int nb) {
    __shared__ int tmp[SCAN_B];
    int v = (threadIdx.x < nb) ? bsum[threadIdx.x] : 0;
    tmp[threadIdx.x] = v;
    __syncthreads();
    for (int off = 1; off < SCAN_B; off <<= 1) {
        int t = (threadIdx.x >= off) ? tmp[threadIdx.x - off] : 0;
        __syncthreads();
        tmp[threadIdx.x] += t;
        __syncthreads();
    }
    if (threadIdx.x < nb) bsum[threadIdx.x] = tmp[threadIdx.x] - v;
}

__global__ void k_scan3(int* __restrict__ out, const int* __restrict__ bsum, int n) {
    int i = blockIdx.x * SCAN_B + threadIdx.x;
    if (i < n) out[i] += bsum[blockIdx.x];
    if (i == 0) out[n] = N_EDGES;
}

// ---------------- CSR fill ----------------
__global__ void k_fill(const int* __restrict__ src, const int* __restrict__ dst,
                       const int* __restrict__ row_start, int* __restrict__ cursor,
                       const float* __restrict__ dis, int* __restrict__ src_sorted,
                       float* __restrict__ norm_sorted) {
    int e = blockIdx.x * blockDim.x + threadIdx.x;
    if (e >= N_EDGES) return;
    int s = src[e], d = dst[e];
    int pos = row_start[d] + atomicAdd(&cursor[d], 1);
    src_sorted[pos] = s;
    norm_sorted[pos] = dis[s] * dis[d];
}

// ---------------- dense GEMM: out[N,128] = in[N,DIN] @ W[DIN,128] ----------------
template <int DIN>
__global__ void k_gemm(const float* __restrict__ in, const float* __restrict__ W,
                       float* __restrict__ out) {
    int col  = threadIdx.x;          // 0..127
    int row0 = blockIdx.x * 4;
    const float* r = in + (size_t)row0 * DIN;
    float a0 = 0.f, a1 = 0.f, a2 = 0.f, a3 = 0.f;
#pragma unroll 8
    for (int k = 0; k < DIN; ++k) {
        float w = W[k * D + col];
        a0 = fmaf(r[k],           w, a0);
        a1 = fmaf(r[DIN + k],     w, a1);
        a2 = fmaf(r[2 * DIN + k], w, a2);
        a3 = fmaf(r[3 * DIN + k], w, a3);
    }
    size_t o = (size_t)row0 * D + col;
    out[o] = a0; out[o + D] = a1; out[o + 2 * D] = a2; out[o + 3 * D] = a3;
}

// ---------------- fused gather + self-loop + bias + relu ----------------
// 8 groups of 32 lanes per block; each group owns one dst node, lane j owns 4 feats.
__global__ void k_gather(const int* __restrict__ row_start, const int* __restrict__ src_sorted,
                         const float* __restrict__ norm_sorted, const float* __restrict__ hw,
                         const float* __restrict__ dis, const float* __restrict__ b,
                         float* __restrict__ out) {
    int node = blockIdx.x * 8 + (threadIdx.x >> 5);
    if (node >= N_NODES) return;
    int j4 = (threadIdx.x & 31) * 4;
    int s0 = row_start[node], s1 = row_start[node + 1];
    float ax = 0.f, ay = 0.f, az = 0.f, aw = 0.f;
    for (int k = s0; k < s1; ++k) {
        int s = src_sorted[k];
        float nm = norm_sorted[k];
        const float4 v = *(const float4*)&hw[(size_t)s * D + j4];
        ax = fmaf(v.x, nm, ax);
        ay = fmaf(v.y, nm, ay);
        az = fmaf(v.z, nm, az);
        aw = fmaf(v.w, nm, aw);
    }
    float dd = dis[node];
    float sl = dd * dd;
    const float4 hv = *(const float4*)&hw[(size_t)node * D + j4];
    const float4 bv = *(const float4*)&b[j4];
    float4 r;
    r.x = fmaxf(fmaf(hv.x, sl, ax) + bv.x, 0.f);
    r.y = fmaxf(fmaf(hv.y, sl, ay) + bv.y, 0.f);
    r.z = fmaxf(fmaf(hv.z, sl, az) + bv.z, 0.f);
    r.w = fmaxf(fmaf(hv.w, sl, aw) + bv.w, 0.f);
    *(float4*)&out[(size_t)node * D + j4] = r;
}

// ---------------- readout ----------------
__global__ void k_counts(const int* __restrict__ batch, float* counts) {
    int n = blockIdx.x * blockDim.x + threadIdx.x;
    if (n < N_NODES) atomicAdd(&counts[batch[n]], 1.0f);
}

__global__ void k_gsum(const int* __restrict__ batch, const float* __restrict__ h,
                       float* __restrict__ gsum) {
    long long i = (long long)blockIdx.x * blockDim.x + threadIdx.x;
    if (i >= (long long)N_NODES * D) return;
    int n = (int)(i >> 7), j = (int)(i & 127);
    atomicAdd(&gsum[(size_t)batch[n] * D + j], h[i]);
}

__global__ void k_gdiv(float* gsum, const float* __restrict__ counts) {
    int i = blockIdx.x * blockDim.x + threadIdx.x;
    if (i >= N_GRAPHS * D) return;
    gsum[i] /= fmaxf(counts[i >> 7], 1.0f);
}

// ---------------- prototypes / distances / logits ----------------
__global__ void k_proto(const float* __restrict__ pe, float* __restrict__ pg) {
    int i = blockIdx.x * blockDim.x + threadIdx.x;   // 6400
    if (i >= N_PROTO * D) return;
    int p = i >> 7, j = i & 127;
    float s = 0.f;
#pragma unroll
    for (int g = 0; g < GRAPH_SZ; ++g) s += pe[((size_t)p * GRAPH_SZ + g) * D + j];
    pg[i] = s * (1.0f / GRAPH_SZ);
}

__global__ void k_sim(const float* __restrict__ ge, const float* __restrict__ pg,
                      float* __restrict__ sim) {
    int t = blockIdx.x * blockDim.x + threadIdx.x;   // 25000
    if (t >= N_GRAPHS * N_PROTO) return;
    int b = t / N_PROTO, p = t % N_PROTO;
    const float* g = ge + (size_t)b * D;
    const float* q = pg + (size_t)p * D;
    float d2 = 0.f;
#pragma unroll 8
    for (int j = 0; j < D; ++j) { float df = g[j] - q[j]; d2 = fmaf(df, df, d2); }
    sim[t] = logf((d2 + 1.0f) / (d2 + EPS_F));
}

__global__ void k_logits(const float* __restrict__ sim, const float* __restrict__ lw,
                         float* __restrict__ out) {
    int t = blockIdx.x * blockDim.x + threadIdx.x;   // 5000
    if (t >= N_GRAPHS * N_CLASSES) return;
    int b = t / N_CLASSES, c = t % N_CLASSES;
    float s = 0.f;
#pragma unroll
    for (int p = 0; p < N_PROTO; ++p) s = fmaf(sim[b * N_PROTO + p], lw[c * N_PROTO + p], s);
    out[t] = s;
}

extern "C" void kernel_launch(void* const* d_in, const int* in_sizes, int n_in,
                              void* d_out, int out_size, void* d_ws, size_t ws_size,
                              hipStream_t stream) {
    const float* x   = (const float*)d_in[0];
    const int*   ei  = (const int*)d_in[1];      // [2, E] flat: src row, dst row
    const int*   bat = (const int*)d_in[2];
    const float* W0  = (const float*)d_in[3];
    const float* b0  = (const float*)d_in[4];
    const float* W1  = (const float*)d_in[5];
    const float* b1  = (const float*)d_in[6];
    const float* W2  = (const float*)d_in[7];
    const float* b2  = (const float*)d_in[8];
    const float* pe  = (const float*)d_in[9];
    const float* lw  = (const float*)d_in[10];
    float* out = (float*)d_out;

    const int* esrc = ei;
    const int* edst = ei + N_EDGES;

    const size_t ND = (size_t)N_NODES * D;
    char* wsb = (char*)d_ws;
    float* buf1        = (float*)wsb;                       wsb += ND * sizeof(float);
    float* buf2        = (float*)wsb;                       wsb += ND * sizeof(float);
    float* dis         = (float*)wsb;                       wsb += N_NODES * sizeof(float);
    float* norm_sorted = (float*)wsb;                       wsb += N_EDGES * sizeof(float);
    int*   src_sorted  = (int*)wsb;                         wsb += N_EDGES * sizeof(int);
    int*   indeg       = (int*)wsb;                         wsb += N_NODES * sizeof(int);   // reused as cursor
    int*   row_start   = (int*)wsb;                         wsb += (N_NODES + 1) * sizeof(int);
    int*   bsum        = (int*)wsb;                         wsb += SCAN_B * sizeof(int);
    float* cnts        = (float*)wsb;                       wsb += N_GRAPHS * sizeof(float);
    float* gsum        = (float*)wsb;                       wsb += (size_t)N_GRAPHS * D * sizeof(float);
    float* pg          = (float*)wsb;                       wsb += N_PROTO * D * sizeof(float);
    float* sim         = (float*)wsb;                       wsb += N_GRAPHS * N_PROTO * sizeof(float);

    const int TB = 256;
    int nd_blocks = (int)((ND + TB - 1) / TB);
    int e_blocks  = (N_EDGES + TB - 1) / TB;
    int n_blocks  = (N_NODES + TB - 1) / TB;
    int s_blocks  = (N_NODES + SCAN_B - 1) / SCAN_B;        // 196

    // ---- CSR build ----
    hipMemsetAsync(indeg, 0, N_NODES * sizeof(int), stream);
    k_count_indeg<<<e_blocks, TB, 0, stream>>>(edst, indeg);
    k_dis<<<n_blocks, TB, 0, stream>>>(indeg, dis);
    k_scan1<<<s_blocks, SCAN_B, 0, stream>>>(indeg, row_start, bsum, N_NODES);
    k_scan2<<<1, SCAN_B, 0, stream>>>(bsum, s_blocks);
    k_scan3<<<s_blocks, SCAN_B, 0, stream>>>(row_start, bsum, N_NODES);
    hipMemsetAsync(indeg, 0, N_NODES * sizeof(int), stream);   // cursor
    k_fill<<<e_blocks, TB, 0, stream>>>(esrc, edst, row_start, indeg, dis,
                                        src_sorted, norm_sorted);

    int g_blocks = (N_NODES + 7) / 8;

    // ---- layer 0 ----
    k_gemm<IN_DIM><<<N_NODES / 4, 128, 0, stream>>>(x, W0, buf1);
    k_gather<<<g_blocks, TB, 0, stream>>>(row_start, src_sorted, norm_sorted,
                                          buf1, dis, b0, buf2);
    // ---- layer 1 ----
    k_gemm<D><<<N_NODES / 4, 128, 0, stream>>>(buf2, W1, buf1);
    k_gather<<<g_blocks, TB, 0, stream>>>(row_start, src_sorted, norm_sorted,
                                          buf1, dis, b1, buf2);
    // ---- layer 2 ----
    k_gemm<D><<<N_NODES / 4, 128, 0, stream>>>(buf2, W2, buf1);
    k_gather<<<g_blocks, TB, 0, stream>>>(row_start, src_sorted, norm_sorted,
                                          buf1, dis, b2, buf2);

    // ---- readout ----
    hipMemsetAsync(cnts, 0, N_GRAPHS * sizeof(float), stream);
    hipMemsetAsync(gsum, 0, (size_t)N_GRAPHS * D * sizeof(float), stream);
    k_counts<<<n_blocks, TB, 0, stream>>>(bat, cnts);
    k_gsum<<<nd_blocks, TB, 0, stream>>>(bat, buf2, gsum);
    k_gdiv<<<(N_GRAPHS * D + TB - 1) / TB, TB, 0, stream>>>(gsum, cnts);

    // ---- prototypes, similarities, logits ----
    k_proto<<<(N_PROTO * D + TB - 1) / TB, TB, 0, stream>>>(pe, pg);
    k_sim<<<(N_GRAPHS * N_PROTO + TB - 1) / TB, TB, 0, stream>>>(gsum, pg, sim);
    k_logits<<<(N_GRAPHS * N_CLASSES + TB - 1) / TB, TB, 0, stream>>>(sim, lw, out);
}

// Round 3
// 265.916 us; speedup vs baseline: 12.5304x; 1.6065x over previous
//
#include <hip/hip_runtime.h>
#include <hip/hip_bf16.h>
#include <hip/hip_fp16.h>

#define N_NODES   50000
#define N_EDGES   600000
#define N_GRAPHS  500
#define IN_DIM    64
#define D         128
#define N_CLASSES 10
#define N_PROTO   50
#define GRAPH_SZ  10
#define EPS_F     1e-4f
#define SCAN_B    256

typedef _Float16 half4_t __attribute__((ext_vector_type(4)));
typedef _Float16 half8_t __attribute__((ext_vector_type(8)));
typedef float    f32x4   __attribute__((ext_vector_type(4)));

// ---------------- degree / dis ----------------
__global__ void k_count_indeg(const int* __restrict__ dst, int* __restrict__ indeg) {
    int e = blockIdx.x * blockDim.x + threadIdx.x;
    if (e < N_EDGES) atomicAdd(&indeg[dst[e]], 1);
}

__global__ void k_dis(const int* __restrict__ indeg, float* __restrict__ dis) {
    int i = blockIdx.x * blockDim.x + threadIdx.x;
    if (i < N_NODES) dis[i] = rsqrtf(1.0f + (float)indeg[i]);
}

// ---------------- exclusive scan (2-level) ----------------
__global__ void k_scan1(const int* __restrict__ in, int* __restrict__ out,
                        int* __restrict__ bsum, int n) {
    __shared__ int tmp[SCAN_B];
    int i = blockIdx.x * SCAN_B + threadIdx.x;
    int v = (i < n) ? in[i] : 0;
    tmp[threadIdx.x] = v;
    __syncthreads();
    for (int off = 1; off < SCAN_B; off <<= 1) {
        int t = (threadIdx.x >= off) ? tmp[threadIdx.x - off] : 0;
        __syncthreads();
        tmp[threadIdx.x] += t;
        __syncthreads();
    }
    if (i < n) out[i] = tmp[threadIdx.x] - v;
    if (threadIdx.x == SCAN_B - 1) bsum[blockIdx.x] = tmp[threadIdx.x];
}

__global__ void k_scan2(int* bsum, int nb) {
    __shared__ int tmp[SCAN_B];
    int v = (threadIdx.x < nb) ? bsum[threadIdx.x] : 0;
    tmp[threadIdx.x] = v;
    __syncthreads();
    for (int off = 1; off < SCAN_B; off <<= 1) {
        int t = (threadIdx.x >= off) ? tmp[threadIdx.x - off] : 0;
        __syncthreads();
        tmp[threadIdx.x] += t;
        __syncthreads();
    }
    if (threadIdx.x < nb) bsum[threadIdx.x] = tmp[threadIdx.x] - v;
}

__global__ void k_scan3(int* __restrict__ out, const int* __restrict__ bsum, int n) {
    int i = blockIdx.x * SCAN_B + threadIdx.x;
    if (i < n) out[i] += bsum[blockIdx.x];
    if (i == 0) out[n] = N_EDGES;
}

// ---------------- CSR fill ----------------
__global__ void k_fill(const int* __restrict__ src, const int* __restrict__ dst,
                       const int* __restrict__ row_start, int* __restrict__ cursor,
                       const float* __restrict__ dis, int* __restrict__ src_sorted,
                       float* __restrict__ norm_sorted) {
    int e = blockIdx.x * blockDim.x + threadIdx.x;
    if (e >= N_EDGES) return;
    int s = src[e], d = dst[e];
    int pos = row_start[d] + atomicAdd(&cursor[d], 1);
    src_sorted[pos] = s;
    norm_sorted[pos] = dis[s] * dis[d];
}

// ---------------- fp32 -> fp16 convert (4 elems/thread) ----------------
__global__ void k_f32_to_f16(const float* __restrict__ in, _Float16* __restrict__ out,
                             int n4) {
    int t = blockIdx.x * blockDim.x + threadIdx.x;
    if (t >= n4) return;
    float4 v = ((const float4*)in)[t];
    half4_t h = { (_Float16)v.x, (_Float16)v.y, (_Float16)v.z, (_Float16)v.w };
    ((half4_t*)out)[t] = h;
}

// ---------------- 64-dim aggregation of x (with self-loop), fp16 ----------------
__global__ void k_agg64(const int* __restrict__ row_start, const int* __restrict__ src_sorted,
                        const float* __restrict__ norm_sorted, const _Float16* __restrict__ xh,
                        const float* __restrict__ dis, _Float16* __restrict__ out) {
    int node = blockIdx.x * 16 + (threadIdx.x >> 4);
    if (node >= N_NODES) return;
    int j4 = (threadIdx.x & 15) * 4;
    int s0 = row_start[node], s1 = row_start[node + 1];
    float a0 = 0.f, a1 = 0.f, a2 = 0.f, a3 = 0.f;
    for (int k = s0; k < s1; ++k) {
        int s = src_sorted[k];
        float nm = norm_sorted[k];
        half4_t v = *(const half4_t*)&xh[(size_t)s * IN_DIM + j4];
        a0 = fmaf((float)v[0], nm, a0);
        a1 = fmaf((float)v[1], nm, a1);
        a2 = fmaf((float)v[2], nm, a2);
        a3 = fmaf((float)v[3], nm, a3);
    }
    float dd = dis[node]; float sl = dd * dd;
    half4_t hv = *(const half4_t*)&xh[(size_t)node * IN_DIM + j4];
    a0 = fmaf((float)hv[0], sl, a0);
    a1 = fmaf((float)hv[1], sl, a1);
    a2 = fmaf((float)hv[2], sl, a2);
    a3 = fmaf((float)hv[3], sl, a3);
    half4_t r = { (_Float16)a0, (_Float16)a1, (_Float16)a2, (_Float16)a3 };
    *(half4_t*)&out[(size_t)node * IN_DIM + j4] = r;
}

// ---------------- W pack: fp32 [K,128] -> fp16 MFMA B-fragment layout ----------------
// Bp[((c*NKS+s)*64 + lane)*8 + j] = W[(s*32 + (lane>>4)*8 + j)*128 + c*16 + (lane&15)]
__global__ void k_pack_w(const float* __restrict__ W, _Float16* __restrict__ Bp, int nks) {
    int t = blockIdx.x * blockDim.x + threadIdx.x;
    if (t >= nks * 8 * 64 * 8) return;
    int j = t & 7, l = (t >> 3) & 63;
    int rest = t >> 9;
    int s = rest % nks, c = rest / nks;
    int k = s * 32 + (l >> 4) * 8 + j;
    int col = c * 16 + (l & 15);
    Bp[t] = (_Float16)W[k * D + col];
}

// ---------------- MFMA GEMM: out[N,128] = A[N,DIN] @ W, fp16 in/out, fp32 accum ----
template <int DIN, bool BIAS_RELU>
__global__ void k_mfma_gemm(const _Float16* __restrict__ A, const _Float16* __restrict__ Bp,
                            const float* __restrict__ bias, _Float16* __restrict__ out) {
    constexpr int NKS = DIN / 32;
    int wave = threadIdx.x >> 6;                 // 0..3
    int lane = threadIdx.x & 63;
    int row0 = blockIdx.x * 64 + wave * 16;
    int arow = row0 + (lane & 15);
    if (arow >= N_NODES) arow = N_NODES - 1;     // clamp; stores guarded
    half8_t afrag[NKS];
    const _Float16* ap = A + (size_t)arow * DIN + (lane >> 4) * 8;
#pragma unroll
    for (int s = 0; s < NKS; ++s) afrag[s] = *(const half8_t*)(ap + s * 32);
    f32x4 acc[8];
#pragma unroll
    for (int c = 0; c < 8; ++c) acc[c] = (f32x4){0.f, 0.f, 0.f, 0.f};
#pragma unroll
    for (int c = 0; c < 8; ++c) {
#pragma unroll
        for (int s = 0; s < NKS; ++s) {
            half8_t b = *(const half8_t*)&Bp[(size_t)((c * NKS + s) * 64 + lane) * 8];
            acc[c] = __builtin_amdgcn_mfma_f32_16x16x32_f16(afrag[s], b, acc[c], 0, 0, 0);
        }
    }
    int rbase = row0 + (lane >> 4) * 4;
    int colb  = lane & 15;
#pragma unroll
    for (int c = 0; c < 8; ++c) {
        int col = c * 16 + colb;
        float bv = BIAS_RELU ? bias[col] : 0.f;
#pragma unroll
        for (int r = 0; r < 4; ++r) {
            int row = rbase + r;
            if (row < N_NODES) {
                float v = acc[c][r] + bv;
                if (BIAS_RELU) v = fmaxf(v, 0.f);
                out[(size_t)row * D + col] = (_Float16)v;
            }
        }
    }
}

// ---------------- fused 128-dim gather + self-loop + bias + relu, fp16 ----------------
__global__ void k_gather128(const int* __restrict__ row_start, const int* __restrict__ src_sorted,
                            const float* __restrict__ norm_sorted, const _Float16* __restrict__ hw,
                            const float* __restrict__ dis, const float* __restrict__ b,
                            _Float16* __restrict__ out) {
    int node = blockIdx.x * 16 + (threadIdx.x >> 4);
    if (node >= N_NODES) return;
    int j8 = (threadIdx.x & 15) * 8;
    int s0 = row_start[node], s1 = row_start[node + 1];
    float a[8] = {0.f, 0.f, 0.f, 0.f, 0.f, 0.f, 0.f, 0.f};
    for (int k = s0; k < s1; ++k) {
        int s = src_sorted[k];
        float nm = norm_sorted[k];
        half8_t v = *(const half8_t*)&hw[(size_t)s * D + j8];
#pragma unroll
        for (int j = 0; j < 8; ++j) a[j] = fmaf((float)v[j], nm, a[j]);
    }
    float dd = dis[node]; float sl = dd * dd;
    half8_t hv = *(const half8_t*)&hw[(size_t)node * D + j8];
    half8_t r;
#pragma unroll
    for (int j = 0; j < 8; ++j) {
        float v = fmaf((float)hv[j], sl, a[j]) + b[j8 + j];
        r[j] = (_Float16)fmaxf(v, 0.f);
    }
    *(half8_t*)&out[(size_t)node * D + j8] = r;
}

// ---------------- segmented mean readout (batch sorted) ----------------
__global__ void k_readout(const int* __restrict__ batch, const _Float16* __restrict__ h,
                          float* __restrict__ ge) {
    __shared__ int sh[2];
    int g = blockIdx.x;
    if (threadIdx.x == 0) {
        int lo = 0, hi = N_NODES;
        while (lo < hi) { int m = (lo + hi) >> 1; if (batch[m] < g) lo = m + 1; else hi = m; }
        sh[0] = lo;
        hi = N_NODES;
        while (lo < hi) { int m = (lo + hi) >> 1; if (batch[m] < g + 1) lo = m + 1; else hi = m; }
        sh[1] = lo;
    }
    __syncthreads();
    int s0 = sh[0], s1 = sh[1];
    int col = threadIdx.x;   // 128 threads
    float sum = 0.f;
    for (int n = s0; n < s1; ++n) sum += (float)h[(size_t)n * D + col];
    ge[(size_t)g * D + col] = sum / fmaxf((float)(s1 - s0), 1.0f);
}

// ---------------- prototypes / sim+logits ----------------
__global__ void k_proto(const float* __restrict__ pe, float* __restrict__ pg) {
    int i = blockIdx.x * blockDim.x + threadIdx.x;   // 6400
    if (i >= N_PROTO * D) return;
    int p = i >> 7, j = i & 127;
    float s = 0.f;
#pragma unroll
    for (int g = 0; g < GRAPH_SZ; ++g) s += pe[((size_t)p * GRAPH_SZ + g) * D + j];
    pg[i] = s * (1.0f / GRAPH_SZ);
}

__global__ void k_simlog(const float* __restrict__ ge, const float* __restrict__ pg,
                         const float* __restrict__ lw, float* __restrict__ out) {
    __shared__ float gs[D];
    __shared__ float sim[N_PROTO];
    int g = blockIdx.x;
    for (int j = threadIdx.x; j < D; j += 64) gs[j] = ge[(size_t)g * D + j];
    __syncthreads();
    if (threadIdx.x < N_PROTO) {
        const float* q = pg + threadIdx.x * D;
        float d2 = 0.f;
#pragma unroll 8
        for (int j = 0; j < D; ++j) { float df = gs[j] - q[j]; d2 = fmaf(df, df, d2); }
        sim[threadIdx.x] = logf((d2 + 1.0f) / (d2 + EPS_F));
    }
    __syncthreads();
    if (threadIdx.x < N_CLASSES) {
        float s = 0.f;
#pragma unroll
        for (int p = 0; p < N_PROTO; ++p) s = fmaf(sim[p], lw[threadIdx.x * N_PROTO + p], s);
        out[(size_t)g * N_CLASSES + threadIdx.x] = s;
    }
}

extern "C" void kernel_launch(void* const* d_in, const int* in_sizes, int n_in,
                              void* d_out, int out_size, void* d_ws, size_t ws_size,
                              hipStream_t stream) {
    const float* x   = (const float*)d_in[0];
    const int*   ei  = (const int*)d_in[1];
    const int*   bat = (const int*)d_in[2];
    const float* W0  = (const float*)d_in[3];
    const float* b0  = (const float*)d_in[4];
    const float* W1  = (const float*)d_in[5];
    const float* b1  = (const float*)d_in[6];
    const float* W2  = (const float*)d_in[7];
    const float* b2  = (const float*)d_in[8];
    const float* pe  = (const float*)d_in[9];
    const float* lw  = (const float*)d_in[10];
    float* out = (float*)d_out;

    const int* esrc = ei;
    const int* edst = ei + N_EDGES;

    char* wsb = (char*)d_ws;
    // 16B-aligned group first
    _Float16* bufA = (_Float16*)wsb;  wsb += (size_t)N_NODES * D * 2;      // hw
    _Float16* bufB = (_Float16*)wsb;  wsb += (size_t)N_NODES * D * 2;      // h
    _Float16* xh   = (_Float16*)wsb;  wsb += (size_t)N_NODES * IN_DIM * 2;
    _Float16* agg0 = (_Float16*)wsb;  wsb += (size_t)N_NODES * IN_DIM * 2;
    _Float16* Bp0  = (_Float16*)wsb;  wsb += (size_t)IN_DIM * D * 2;
    _Float16* Bp1  = (_Float16*)wsb;  wsb += (size_t)D * D * 2;
    _Float16* Bp2  = (_Float16*)wsb;  wsb += (size_t)D * D * 2;
    float* ge      = (float*)wsb;     wsb += (size_t)N_GRAPHS * D * 4;
    float* pg      = (float*)wsb;     wsb += (size_t)N_PROTO * D * 4;
    float* dis     = (float*)wsb;     wsb += (size_t)N_NODES * 4;
    float* norm_sorted = (float*)wsb; wsb += (size_t)N_EDGES * 4;
    int*   src_sorted  = (int*)wsb;   wsb += (size_t)N_EDGES * 4;
    int*   indeg   = (int*)wsb;       wsb += (size_t)N_NODES * 4;          // reused as cursor
    int*   row_start = (int*)wsb;     wsb += (size_t)(N_NODES + 1) * 4;
    int*   bsum    = (int*)wsb;       wsb += (size_t)SCAN_B * 4;

    const int TB = 256;
    int e_blocks = (N_EDGES + TB - 1) / TB;
    int n_blocks = (N_NODES + TB - 1) / TB;
    int s_blocks = (N_NODES + SCAN_B - 1) / SCAN_B;
    int grp_blocks = (N_NODES + 15) / 16;          // 16 node-groups per block
    int gemm_blocks = (N_NODES + 63) / 64;

    // ---- CSR build ----
    hipMemsetAsync(indeg, 0, N_NODES * sizeof(int), stream);
    k_count_indeg<<<e_blocks, TB, 0, stream>>>(edst, indeg);
    k_dis<<<n_blocks, TB, 0, stream>>>(indeg, dis);
    k_scan1<<<s_blocks, SCAN_B, 0, stream>>>(indeg, row_start, bsum, N_NODES);
    k_scan2<<<1, SCAN_B, 0, stream>>>(bsum, s_blocks);
    k_scan3<<<s_blocks, SCAN_B, 0, stream>>>(row_start, bsum, N_NODES);
    hipMemsetAsync(indeg, 0, N_NODES * sizeof(int), stream);
    k_fill<<<e_blocks, TB, 0, stream>>>(esrc, edst, row_start, indeg, dis,
                                        src_sorted, norm_sorted);

    // ---- input + weight conversion ----
    k_f32_to_f16<<<(N_NODES * IN_DIM / 4 + TB - 1) / TB, TB, 0, stream>>>(x, xh,
                                                                          N_NODES * IN_DIM / 4);
    k_pack_w<<<(IN_DIM * D + TB - 1) / TB, TB, 0, stream>>>(W0, Bp0, IN_DIM / 32);
    k_pack_w<<<(D * D + TB - 1) / TB, TB, 0, stream>>>(W1, Bp1, D / 32);
    k_pack_w<<<(D * D + TB - 1) / TB, TB, 0, stream>>>(W2, Bp2, D / 32);

    // ---- layer 0: aggregate-first (64-dim), then GEMM + bias + relu ----
    k_agg64<<<grp_blocks, TB, 0, stream>>>(row_start, src_sorted, norm_sorted, xh, dis, agg0);
    k_mfma_gemm<IN_DIM, true><<<gemm_blocks, TB, 0, stream>>>(agg0, Bp0, b0, bufB);

    // ---- layer 1: GEMM, gather(+bias+relu) ----
    k_mfma_gemm<D, false><<<gemm_blocks, TB, 0, stream>>>(bufB, Bp1, nullptr, bufA);
    k_gather128<<<grp_blocks, TB, 0, stream>>>(row_start, src_sorted, norm_sorted,
                                               bufA, dis, b1, bufB);
    // ---- layer 2 ----
    k_mfma_gemm<D, false><<<gemm_blocks, TB, 0, stream>>>(bufB, Bp2, nullptr, bufA);
    k_gather128<<<grp_blocks, TB, 0, stream>>>(row_start, src_sorted, norm_sorted,
                                               bufA, dis, b2, bufB);

    // ---- readout / prototypes / logits ----
    k_readout<<<N_GRAPHS, D, 0, stream>>>(bat, bufB, ge);
    k_proto<<<(N_PROTO * D + TB - 1) / TB, TB, 0, stream>>>(pe, pg);
    k_simlog<<<N_GRAPHS, 64, 0, stream>>>(ge, pg, lw, out);
}

// Round 5
// 210.287 us; speedup vs baseline: 15.8451x; 1.2645x over previous
//
#include <hip/hip_runtime.h>
#include <hip/hip_bf16.h>
#include <hip/hip_fp16.h>

#define N_NODES   50000
#define N_EDGES   600000
#define N_GRAPHS  500
#define IN_DIM    64
#define D         128
#define N_CLASSES 10
#define N_PROTO   50
#define GRAPH_SZ  10
#define EPS_F     1e-4f
#define SCAN_B    256

typedef _Float16 half4_t __attribute__((ext_vector_type(4)));
typedef _Float16 half8_t __attribute__((ext_vector_type(8)));
typedef float    f32x4   __attribute__((ext_vector_type(4)));

// ---------------- zero (replaces slow rocclr fills) ----------------
__global__ void k_zero(int* __restrict__ p, int n) {
    int i = blockIdx.x * blockDim.x + threadIdx.x;
    if (i < n) p[i] = 0;
}

// ---------------- degree ----------------
__global__ void k_count_indeg(const int* __restrict__ dst, int* __restrict__ indeg) {
    int e = blockIdx.x * blockDim.x + threadIdx.x;
    if (e < N_EDGES) atomicAdd(&indeg[dst[e]], 1);
}

// ---------------- exclusive scan (2-level) + dis fused ----------------
__global__ void k_scan1(const int* __restrict__ in, int* __restrict__ out,
                        int* __restrict__ bsum, float* __restrict__ dis, int n) {
    __shared__ int tmp[SCAN_B];
    int i = blockIdx.x * SCAN_B + threadIdx.x;
    int v = (i < n) ? in[i] : 0;
    if (i < n) dis[i] = rsqrtf(1.0f + (float)v);
    tmp[threadIdx.x] = v;
    __syncthreads();
    for (int off = 1; off < SCAN_B; off <<= 1) {
        int t = (threadIdx.x >= off) ? tmp[threadIdx.x - off] : 0;
        __syncthreads();
        tmp[threadIdx.x] += t;
        __syncthreads();
    }
    if (i < n) out[i] = tmp[threadIdx.x] - v;
    if (threadIdx.x == SCAN_B - 1) bsum[blockIdx.x] = tmp[threadIdx.x];
}

__global__ void k_scan2(int* bsum, int nb) {
    __shared__ int tmp[SCAN_B];
    int v = (threadIdx.x < nb) ? bsum[threadIdx.x] : 0;
    tmp[threadIdx.x] = v;
    __syncthreads();
    for (int off = 1; off < SCAN_B; off <<= 1) {
        int t = (threadIdx.x >= off) ? tmp[threadIdx.x - off] : 0;
        __syncthreads();
        tmp[threadIdx.x] += t;
        __syncthreads();
    }
    if (threadIdx.x < nb) bsum[threadIdx.x] = tmp[threadIdx.x] - v;
}

__global__ void k_scan3(int* __restrict__ out, const int* __restrict__ bsum, int n) {
    int i = blockIdx.x * SCAN_B + threadIdx.x;
    if (i < n) out[i] += bsum[blockIdx.x];
    if (i == 0) out[n] = N_EDGES;
}

// ---------------- CSR fill ----------------
__global__ void k_fill(const int* __restrict__ src, const int* __restrict__ dst,
                       const int* __restrict__ row_start, int* __restrict__ cursor,
                       const float* __restrict__ dis, int* __restrict__ src_sorted,
                       float* __restrict__ norm_sorted) {
    int e = blockIdx.x * blockDim.x + threadIdx.x;
    if (e >= N_EDGES) return;
    int s = src[e], d = dst[e];
    int pos = row_start[d] + atomicAdd(&cursor[d], 1);
    src_sorted[pos] = s;
    norm_sorted[pos] = dis[s] * dis[d];
}

// ---------------- fp32 -> fp16 convert ----------------
__global__ void k_f32_to_f16(const float* __restrict__ in, _Float16* __restrict__ out,
                             int n4) {
    int t = blockIdx.x * blockDim.x + threadIdx.x;
    if (t >= n4) return;
    float4 v = ((const float4*)in)[t];
    half4_t h = { (_Float16)v.x, (_Float16)v.y, (_Float16)v.z, (_Float16)v.w };
    ((half4_t*)out)[t] = h;
}

// ---------------- pack W (B-fragment layout) helper ----------------
__device__ __forceinline__ void pack_one(const float* __restrict__ W,
                                         _Float16* __restrict__ Bp, int nks, int t) {
    int j = t & 7, l = (t >> 3) & 63;
    int rest = t >> 9;
    int s = rest % nks, c = rest / nks;
    int k = s * 32 + (l >> 4) * 8 + j;
    int col = c * 16 + (l & 15);
    Bp[t] = (_Float16)W[k * D + col];
}

// pack all 3 weights + prototype means in one launch
// ranges: [0,8192) Bp0 | [8192,24576) Bp1 | [24576,40960) Bp2 | [40960,47360) pg
__global__ void k_pack_all(const float* __restrict__ W0, const float* __restrict__ W1,
                           const float* __restrict__ W2, const float* __restrict__ pe,
                           _Float16* __restrict__ Bp0, _Float16* __restrict__ Bp1,
                           _Float16* __restrict__ Bp2, float* __restrict__ pg) {
    int t = blockIdx.x * blockDim.x + threadIdx.x;
    if (t < 8192) {
        pack_one(W0, Bp0, IN_DIM / 32, t);
    } else if (t < 24576) {
        pack_one(W1, Bp1, D / 32, t - 8192);
    } else if (t < 40960) {
        pack_one(W2, Bp2, D / 32, t - 24576);
    } else if (t < 40960 + N_PROTO * D) {
        int i = t - 40960;
        int p = i >> 7, j = i & 127;
        float s = 0.f;
#pragma unroll
        for (int g = 0; g < GRAPH_SZ; ++g) s += pe[((size_t)p * GRAPH_SZ + g) * D + j];
        pg[i] = s * (1.0f / GRAPH_SZ);
    }
}

// ---------------- 64-dim aggregation of x (with self-loop), fp16 ----------------
__global__ void k_agg64(const int* __restrict__ row_start, const int* __restrict__ src_sorted,
                        const float* __restrict__ norm_sorted, const _Float16* __restrict__ xh,
                        const float* __restrict__ dis, _Float16* __restrict__ out) {
    int node = blockIdx.x * 16 + (threadIdx.x >> 4);
    if (node >= N_NODES) return;
    int j4 = (threadIdx.x & 15) * 4;
    int s0 = row_start[node], s1 = row_start[node + 1];
    float a0 = 0.f, a1 = 0.f, a2 = 0.f, a3 = 0.f;
    if (s0 < s1) {
        int s_cur = src_sorted[s0];
        float nm_cur = norm_sorted[s0];
        half4_t v_cur = *(const half4_t*)&xh[(size_t)s_cur * IN_DIM + j4];
        for (int k = s0 + 1; k < s1; ++k) {
            int s_nxt = src_sorted[k];
            float nm_nxt = norm_sorted[k];
            half4_t v_nxt = *(const half4_t*)&xh[(size_t)s_nxt * IN_DIM + j4];
            a0 = fmaf((float)v_cur[0], nm_cur, a0);
            a1 = fmaf((float)v_cur[1], nm_cur, a1);
            a2 = fmaf((float)v_cur[2], nm_cur, a2);
            a3 = fmaf((float)v_cur[3], nm_cur, a3);
            v_cur = v_nxt; nm_cur = nm_nxt;
        }
        a0 = fmaf((float)v_cur[0], nm_cur, a0);
        a1 = fmaf((float)v_cur[1], nm_cur, a1);
        a2 = fmaf((float)v_cur[2], nm_cur, a2);
        a3 = fmaf((float)v_cur[3], nm_cur, a3);
    }
    float dd = dis[node]; float sl = dd * dd;
    half4_t hv = *(const half4_t*)&xh[(size_t)node * IN_DIM + j4];
    a0 = fmaf((float)hv[0], sl, a0);
    a1 = fmaf((float)hv[1], sl, a1);
    a2 = fmaf((float)hv[2], sl, a2);
    a3 = fmaf((float)hv[3], sl, a3);
    half4_t r = { (_Float16)a0, (_Float16)a1, (_Float16)a2, (_Float16)a3 };
    *(half4_t*)&out[(size_t)node * IN_DIM + j4] = r;
}

// ---------------- MFMA GEMM: out[N,128] = A[N,DIN] @ W, fp16 in/out, fp32 accum ----
template <int DIN, bool BIAS_RELU>
__global__ void k_mfma_gemm(const _Float16* __restrict__ A, const _Float16* __restrict__ Bp,
                            const float* __restrict__ bias, _Float16* __restrict__ out) {
    constexpr int NKS = DIN / 32;
    int wave = threadIdx.x >> 6;
    int lane = threadIdx.x & 63;
    int row0 = blockIdx.x * 64 + wave * 16;
    int arow = row0 + (lane & 15);
    if (arow >= N_NODES) arow = N_NODES - 1;
    half8_t afrag[NKS];
    const _Float16* ap = A + (size_t)arow * DIN + (lane >> 4) * 8;
#pragma unroll
    for (int s = 0; s < NKS; ++s) afrag[s] = *(const half8_t*)(ap + s * 32);
    f32x4 acc[8];
#pragma unroll
    for (int c = 0; c < 8; ++c) acc[c] = (f32x4){0.f, 0.f, 0.f, 0.f};
#pragma unroll
    for (int c = 0; c < 8; ++c) {
#pragma unroll
        for (int s = 0; s < NKS; ++s) {
            half8_t b = *(const half8_t*)&Bp[(size_t)((c * NKS + s) * 64 + lane) * 8];
            acc[c] = __builtin_amdgcn_mfma_f32_16x16x32_f16(afrag[s], b, acc[c], 0, 0, 0);
        }
    }
    int rbase = row0 + (lane >> 4) * 4;
    int colb  = lane & 15;
#pragma unroll
    for (int c = 0; c < 8; ++c) {
        int col = c * 16 + colb;
        float bv = BIAS_RELU ? bias[col] : 0.f;
#pragma unroll
        for (int r = 0; r < 4; ++r) {
            int row = rbase + r;
            if (row < N_NODES) {
                float v = acc[c][r] + bv;
                if (BIAS_RELU) v = fmaxf(v, 0.f);
                out[(size_t)row * D + col] = (_Float16)v;
            }
        }
    }
}

// ---------------- fused 128-dim gather + self-loop + bias + relu, fp16 ----------------
__global__ void k_gather128(const int* __restrict__ row_start, const int* __restrict__ src_sorted,
                            const float* __restrict__ norm_sorted, const _Float16* __restrict__ hw,
                            const float* __restrict__ dis, const float* __restrict__ b,
                            _Float16* __restrict__ out) {
    int node = blockIdx.x * 16 + (threadIdx.x >> 4);
    if (node >= N_NODES) return;
    int j8 = (threadIdx.x & 15) * 8;
    int s0 = row_start[node], s1 = row_start[node + 1];
    float a[8] = {0.f, 0.f, 0.f, 0.f, 0.f, 0.f, 0.f, 0.f};
    if (s0 < s1) {
        int s_cur = src_sorted[s0];
        float nm_cur = norm_sorted[s0];
        half8_t v_cur = *(const half8_t*)&hw[(size_t)s_cur * D + j8];
        for (int k = s0 + 1; k < s1; ++k) {
            int s_nxt = src_sorted[k];
            float nm_nxt = norm_sorted[k];
            half8_t v_nxt = *(const half8_t*)&hw[(size_t)s_nxt * D + j8];
#pragma unroll
            for (int j = 0; j < 8; ++j) a[j] = fmaf((float)v_cur[j], nm_cur, a[j]);
            v_cur = v_nxt; nm_cur = nm_nxt;
        }
#pragma unroll
        for (int j = 0; j < 8; ++j) a[j] = fmaf((float)v_cur[j], nm_cur, a[j]);
    }
    float dd = dis[node]; float sl = dd * dd;
    half8_t hv = *(const half8_t*)&hw[(size_t)node * D + j8];
    half8_t r;
#pragma unroll
    for (int j = 0; j < 8; ++j) {
        float v = fmaf((float)hv[j], sl, a[j]) + b[j8 + j];
        r[j] = (_Float16)fmaxf(v, 0.f);
    }
    *(half8_t*)&out[(size_t)node * D + j8] = r;
}

// ---------------- segmented mean readout (batch sorted), 512 thr ----------------
__global__ void k_readout(const int* __restrict__ batch, const _Float16* __restrict__ h,
                          float* __restrict__ ge) {
    __shared__ int sh[2];
    __shared__ float red[4][D];
    int g = blockIdx.x;
    if (threadIdx.x == 0) {
        int lo = 0, hi = N_NODES;
        while (lo < hi) { int m = (lo + hi) >> 1; if (batch[m] < g) lo = m + 1; else hi = m; }
        sh[0] = lo;
        hi = N_NODES;
        while (lo < hi) { int m = (lo + hi) >> 1; if (batch[m] < g + 1) lo = m + 1; else hi = m; }
        sh[1] = lo;
    }
    __syncthreads();
    int s0 = sh[0], s1 = sh[1];
    int col = threadIdx.x & 127;
    int part = threadIdx.x >> 7;          // 0..3
    float sum = 0.f;
    for (int n = s0 + part; n < s1; n += 4) sum += (float)h[(size_t)n * D + col];
    red[part][col] = sum;
    __syncthreads();
    if (part == 0) {
        float tot = sum + red[1][col] + red[2][col] + red[3][col];
        ge[(size_t)g * D + col] = tot / fmaxf((float)(s1 - s0), 1.0f);
    }
}

// ---------------- sim + logits ----------------
__global__ void k_simlog(const float* __restrict__ ge, const float* __restrict__ pg,
                         const float* __restrict__ lw, float* __restrict__ out) {
    __shared__ float gs[D];
    __shared__ float sim[N_PROTO];
    int g = blockIdx.x;
    for (int j = threadIdx.x; j < D; j += 64) gs[j] = ge[(size_t)g * D + j];
    __syncthreads();
    if (threadIdx.x < N_PROTO) {
        const float* q = pg + threadIdx.x * D;
        float d2 = 0.f;
#pragma unroll 8
        for (int j = 0; j < D; ++j) { float df = gs[j] - q[j]; d2 = fmaf(df, df, d2); }
        sim[threadIdx.x] = logf((d2 + 1.0f) / (d2 + EPS_F));
    }
    __syncthreads();
    if (threadIdx.x < N_CLASSES) {
        float s = 0.f;
#pragma unroll
        for (int p = 0; p < N_PROTO; ++p) s = fmaf(sim[p], lw[threadIdx.x * N_PROTO + p], s);
        out[(size_t)g * N_CLASSES + threadIdx.x] = s;
    }
}

extern "C" void kernel_launch(void* const* d_in, const int* in_sizes, int n_in,
                              void* d_out, int out_size, void* d_ws, size_t ws_size,
                              hipStream_t stream) {
    const float* x   = (const float*)d_in[0];
    const int*   ei  = (const int*)d_in[1];
    const int*   bat = (const int*)d_in[2];
    const float* W0  = (const float*)d_in[3];
    const float* b0  = (const float*)d_in[4];
    const float* W1  = (const float*)d_in[5];
    const float* b1  = (const float*)d_in[6];
    const float* W2  = (const float*)d_in[7];
    const float* b2  = (const float*)d_in[8];
    const float* pe  = (const float*)d_in[9];
    const float* lw  = (const float*)d_in[10];
    float* out = (float*)d_out;

    const int* esrc = ei;
    const int* edst = ei + N_EDGES;

    char* wsb = (char*)d_ws;
    _Float16* bufA = (_Float16*)wsb;  wsb += (size_t)N_NODES * D * 2;
    _Float16* bufB = (_Float16*)wsb;  wsb += (size_t)N_NODES * D * 2;
    _Float16* xh   = (_Float16*)wsb;  wsb += (size_t)N_NODES * IN_DIM * 2;
    _Float16* agg0 = (_Float16*)wsb;  wsb += (size_t)N_NODES * IN_DIM * 2;
    _Float16* Bp0  = (_Float16*)wsb;  wsb += (size_t)IN_DIM * D * 2;
    _Float16* Bp1  = (_Float16*)wsb;  wsb += (size_t)D * D * 2;
    _Float16* Bp2  = (_Float16*)wsb;  wsb += (size_t)D * D * 2;
    float* ge      = (float*)wsb;     wsb += (size_t)N_GRAPHS * D * 4;
    float* pg      = (float*)wsb;     wsb += (size_t)N_PROTO * D * 4;
    float* dis     = (float*)wsb;     wsb += (size_t)N_NODES * 4;
    float* norm_sorted = (float*)wsb; wsb += (size_t)N_EDGES * 4;
    int*   src_sorted  = (int*)wsb;   wsb += (size_t)N_EDGES * 4;
    int*   indeg   = (int*)wsb;       wsb += (size_t)N_NODES * 4;
    int*   cursor  = (int*)wsb;       wsb += (size_t)N_NODES * 4;   // adjacent to indeg
    int*   row_start = (int*)wsb;     wsb += (size_t)(N_NODES + 1) * 4;
    int*   bsum    = (int*)wsb;       wsb += (size_t)SCAN_B * 4;

    const int TB = 256;
    int e_blocks = (N_EDGES + TB - 1) / TB;
    int s_blocks = (N_NODES + SCAN_B - 1) / SCAN_B;
    int grp_blocks = (N_NODES + 15) / 16;
    int gemm_blocks = (N_NODES + 63) / 64;

    // ---- CSR build ----
    k_zero<<<(2 * N_NODES + TB - 1) / TB, TB, 0, stream>>>(indeg, 2 * N_NODES);
    k_count_indeg<<<e_blocks, TB, 0, stream>>>(edst, indeg);
    k_scan1<<<s_blocks, SCAN_B, 0, stream>>>(indeg, row_start, bsum, dis, N_NODES);
    k_scan2<<<1, SCAN_B, 0, stream>>>(bsum, s_blocks);
    k_scan3<<<s_blocks, SCAN_B, 0, stream>>>(row_start, bsum, N_NODES);
    k_fill<<<e_blocks, TB, 0, stream>>>(esrc, edst, row_start, cursor, dis,
                                        src_sorted, norm_sorted);

    // ---- conversions / packs / proto ----
    k_f32_to_f16<<<(N_NODES * IN_DIM / 4 + TB - 1) / TB, TB, 0, stream>>>(x, xh,
                                                                          N_NODES * IN_DIM / 4);
    k_pack_all<<<(40960 + N_PROTO * D + TB - 1) / TB, TB, 0, stream>>>(W0, W1, W2, pe,
                                                                       Bp0, Bp1, Bp2, pg);

    // ---- layer 0: aggregate-first (64-dim), then GEMM + bias + relu ----
    k_agg64<<<grp_blocks, TB, 0, stream>>>(row_start, src_sorted, norm_sorted, xh, dis, agg0);
    k_mfma_gemm<IN_DIM, true><<<gemm_blocks, TB, 0, stream>>>(agg0, Bp0, b0, bufB);

    // ---- layer 1 ----
    k_mfma_gemm<D, false><<<gemm_blocks, TB, 0, stream>>>(bufB, Bp1, nullptr, bufA);
    k_gather128<<<grp_blocks, TB, 0, stream>>>(row_start, src_sorted, norm_sorted,
                                               bufA, dis, b1, bufB);
    // ---- layer 2 ----
    k_mfma_gemm<D, false><<<gemm_blocks, TB, 0, stream>>>(bufB, Bp2, nullptr, bufA);
    k_gather128<<<grp_blocks, TB, 0, stream>>>(row_start, src_sorted, norm_sorted,
                                               bufA, dis, b2, bufB);

    // ---- readout / logits ----
    k_readout<<<N_GRAPHS, 512, 0, stream>>>(bat, bufB, ge);
    k_simlog<<<N_GRAPHS, 64, 0, stream>>>(ge, pg, lw, out);
}

// Round 6
// 200.857 us; speedup vs baseline: 16.5891x; 1.0469x over previous
//
#include <hip/hip_runtime.h>
#include <hip/hip_bf16.h>
#include <hip/hip_fp16.h>

#define N_NODES   50000
#define N_EDGES   600000
#define N_GRAPHS  500
#define IN_DIM    64
#define D         128
#define N_CLASSES 10
#define N_PROTO   50
#define GRAPH_SZ  10
#define EPS_F     1e-4f
#define SCAN_B    256

typedef _Float16 half4_t __attribute__((ext_vector_type(4)));
typedef _Float16 half8_t __attribute__((ext_vector_type(8)));
typedef float    f32x4   __attribute__((ext_vector_type(4)));

// ---------------- zero ----------------
__global__ void k_zero(int* __restrict__ p, int n) {
    int i = blockIdx.x * blockDim.x + threadIdx.x;
    if (i < n) p[i] = 0;
}

// ---------------- degree ----------------
__global__ void k_count_indeg(const int* __restrict__ dst, int* __restrict__ indeg) {
    int e = blockIdx.x * blockDim.x + threadIdx.x;
    if (e < N_EDGES) atomicAdd(&indeg[dst[e]], 1);
}

// ---------------- scan1: per-block exclusive scan + dis ----------------
__global__ void k_scan1(const int* __restrict__ in, int* __restrict__ out,
                        int* __restrict__ bsum, float* __restrict__ dis, int n) {
    __shared__ int tmp[SCAN_B];
    int i = blockIdx.x * SCAN_B + threadIdx.x;
    int v = (i < n) ? in[i] : 0;
    if (i < n) dis[i] = rsqrtf(1.0f + (float)v);
    tmp[threadIdx.x] = v;
    __syncthreads();
    for (int off = 1; off < SCAN_B; off <<= 1) {
        int t = (threadIdx.x >= off) ? tmp[threadIdx.x - off] : 0;
        __syncthreads();
        tmp[threadIdx.x] += t;
        __syncthreads();
    }
    if (i < n) out[i] = tmp[threadIdx.x] - v;
    if (threadIdx.x == SCAN_B - 1) bsum[blockIdx.x] = tmp[threadIdx.x];
}

// ---------------- scan23: each block adds prefix of bsum[0..b) ----------------
__global__ void k_scan23(int* __restrict__ out, const int* __restrict__ bsum, int n) {
    __shared__ int red[4];
    __shared__ int spre;
    int b = blockIdx.x;
    int v = 0;
    for (int i = threadIdx.x; i < b; i += SCAN_B) v += bsum[i];
#pragma unroll
    for (int off = 32; off; off >>= 1) v += __shfl_down(v, off);
    if ((threadIdx.x & 63) == 0) red[threadIdx.x >> 6] = v;
    __syncthreads();
    if (threadIdx.x == 0) spre = red[0] + red[1] + red[2] + red[3];
    __syncthreads();
    int i = b * SCAN_B + threadIdx.x;
    if (i < n) out[i] += spre;
    if (i == 0) out[n] = N_EDGES;
}

// ---------------- CSR fill ----------------
__global__ void k_fill(const int* __restrict__ src, const int* __restrict__ dst,
                       const int* __restrict__ row_start, int* __restrict__ cursor,
                       const float* __restrict__ dis, int* __restrict__ src_sorted,
                       float* __restrict__ norm_sorted) {
    int e = blockIdx.x * blockDim.x + threadIdx.x;
    if (e >= N_EDGES) return;
    int s = src[e], d = dst[e];
    int pos = row_start[d] + atomicAdd(&cursor[d], 1);
    src_sorted[pos] = s;
    norm_sorted[pos] = dis[s] * dis[d];
}

// ---------------- pack W (B-fragment layout) helper ----------------
__device__ __forceinline__ void pack_one(const float* __restrict__ W,
                                         _Float16* __restrict__ Bp, int nks, int t) {
    int j = t & 7, l = (t >> 3) & 63;
    int rest = t >> 9;
    int s = rest % nks, c = rest / nks;
    int k = s * 32 + (l >> 4) * 8 + j;
    int col = c * 16 + (l & 15);
    Bp[t] = (_Float16)W[k * D + col];
}

// conv (x->fp16) + pack all 3 weights + prototype means, one launch
#define NC4 (N_NODES * IN_DIM / 4)   // 800000
__global__ void k_prep(const float* __restrict__ x, _Float16* __restrict__ xh,
                       const float* __restrict__ W0, const float* __restrict__ W1,
                       const float* __restrict__ W2, const float* __restrict__ pe,
                       _Float16* __restrict__ Bp0, _Float16* __restrict__ Bp1,
                       _Float16* __restrict__ Bp2, float* __restrict__ pg) {
    int t = blockIdx.x * blockDim.x + threadIdx.x;
    if (t < NC4) {
        float4 v = ((const float4*)x)[t];
        half4_t h = { (_Float16)v.x, (_Float16)v.y, (_Float16)v.z, (_Float16)v.w };
        ((half4_t*)xh)[t] = h;
        return;
    }
    t -= NC4;
    if (t < 8192) { pack_one(W0, Bp0, IN_DIM / 32, t); return; }
    t -= 8192;
    if (t < 16384) { pack_one(W1, Bp1, D / 32, t); return; }
    t -= 16384;
    if (t < 16384) { pack_one(W2, Bp2, D / 32, t); return; }
    t -= 16384;
    if (t < N_PROTO * D) {
        int p = t >> 7, j = t & 127;
        float s = 0.f;
#pragma unroll
        for (int g = 0; g < GRAPH_SZ; ++g) s += pe[((size_t)p * GRAPH_SZ + g) * D + j];
        pg[t] = s * (1.0f / GRAPH_SZ);
    }
}

// ---------------- 64-dim aggregation of x (split-edge, 32 lanes/node) ----------------
__global__ void k_agg64(const int* __restrict__ row_start, const int* __restrict__ src_sorted,
                        const float* __restrict__ norm_sorted, const _Float16* __restrict__ xh,
                        const float* __restrict__ dis, _Float16* __restrict__ out) {
    int node = blockIdx.x * 8 + (threadIdx.x >> 5);
    if (node >= N_NODES) return;
    int lane16 = threadIdx.x & 15;
    int half   = (threadIdx.x >> 4) & 1;
    int j4 = lane16 * 4;
    int s0 = row_start[node], s1 = row_start[node + 1];
    float a0 = 0.f, a1 = 0.f, a2 = 0.f, a3 = 0.f;
    int k = s0 + half;
    if (k < s1) {
        int sc = src_sorted[k]; float nc = norm_sorted[k];
        half4_t vc = *(const half4_t*)&xh[(size_t)sc * IN_DIM + j4];
        for (k += 2; k < s1; k += 2) {
            int sn = src_sorted[k]; float nn = norm_sorted[k];
            half4_t vn = *(const half4_t*)&xh[(size_t)sn * IN_DIM + j4];
            a0 = fmaf((float)vc[0], nc, a0);
            a1 = fmaf((float)vc[1], nc, a1);
            a2 = fmaf((float)vc[2], nc, a2);
            a3 = fmaf((float)vc[3], nc, a3);
            vc = vn; nc = nn;
        }
        a0 = fmaf((float)vc[0], nc, a0);
        a1 = fmaf((float)vc[1], nc, a1);
        a2 = fmaf((float)vc[2], nc, a2);
        a3 = fmaf((float)vc[3], nc, a3);
    }
    a0 += __shfl_xor(a0, 16);
    a1 += __shfl_xor(a1, 16);
    a2 += __shfl_xor(a2, 16);
    a3 += __shfl_xor(a3, 16);
    if (half == 0) {
        float dd = dis[node]; float sl = dd * dd;
        half4_t hv = *(const half4_t*)&xh[(size_t)node * IN_DIM + j4];
        a0 = fmaf((float)hv[0], sl, a0);
        a1 = fmaf((float)hv[1], sl, a1);
        a2 = fmaf((float)hv[2], sl, a2);
        a3 = fmaf((float)hv[3], sl, a3);
        half4_t r = { (_Float16)a0, (_Float16)a1, (_Float16)a2, (_Float16)a3 };
        *(half4_t*)&out[(size_t)node * IN_DIM + j4] = r;
    }
}

// ---------------- MFMA GEMM: out[N,128] = A[N,DIN] @ W ----------------
template <int DIN, bool BIAS_RELU>
__global__ void k_mfma_gemm(const _Float16* __restrict__ A, const _Float16* __restrict__ Bp,
                            const float* __restrict__ bias, _Float16* __restrict__ out) {
    constexpr int NKS = DIN / 32;
    int wave = threadIdx.x >> 6;
    int lane = threadIdx.x & 63;
    int row0 = blockIdx.x * 64 + wave * 16;
    int arow = row0 + (lane & 15);
    if (arow >= N_NODES) arow = N_NODES - 1;
    half8_t afrag[NKS];
    const _Float16* ap = A + (size_t)arow * DIN + (lane >> 4) * 8;
#pragma unroll
    for (int s = 0; s < NKS; ++s) afrag[s] = *(const half8_t*)(ap + s * 32);
    f32x4 acc[8];
#pragma unroll
    for (int c = 0; c < 8; ++c) acc[c] = (f32x4){0.f, 0.f, 0.f, 0.f};
#pragma unroll
    for (int c = 0; c < 8; ++c) {
#pragma unroll
        for (int s = 0; s < NKS; ++s) {
            half8_t b = *(const half8_t*)&Bp[(size_t)((c * NKS + s) * 64 + lane) * 8];
            acc[c] = __builtin_amdgcn_mfma_f32_16x16x32_f16(afrag[s], b, acc[c], 0, 0, 0);
        }
    }
    int rbase = row0 + (lane >> 4) * 4;
    int colb  = lane & 15;
#pragma unroll
    for (int c = 0; c < 8; ++c) {
        int col = c * 16 + colb;
        float bv = BIAS_RELU ? bias[col] : 0.f;
#pragma unroll
        for (int r = 0; r < 4; ++r) {
            int row = rbase + r;
            if (row < N_NODES) {
                float v = acc[c][r] + bv;
                if (BIAS_RELU) v = fmaxf(v, 0.f);
                out[(size_t)row * D + col] = (_Float16)v;
            }
        }
    }
}

// ---------------- 128-dim gather (split-edge, 32 lanes/node) + self + bias + relu ----
__global__ void k_gather128(const int* __restrict__ row_start, const int* __restrict__ src_sorted,
                            const float* __restrict__ norm_sorted, const _Float16* __restrict__ hw,
                            const float* __restrict__ dis, const float* __restrict__ b,
                            _Float16* __restrict__ out) {
    int node = blockIdx.x * 8 + (threadIdx.x >> 5);
    if (node >= N_NODES) return;
    int lane16 = threadIdx.x & 15;
    int half   = (threadIdx.x >> 4) & 1;
    int j8 = lane16 * 8;
    int s0 = row_start[node], s1 = row_start[node + 1];
    float a[8] = {0.f, 0.f, 0.f, 0.f, 0.f, 0.f, 0.f, 0.f};
    int k = s0 + half;
    if (k < s1) {
        int sc = src_sorted[k]; float nc = norm_sorted[k];
        half8_t vc = *(const half8_t*)&hw[(size_t)sc * D + j8];
        for (k += 2; k < s1; k += 2) {
            int sn = src_sorted[k]; float nn = norm_sorted[k];
            half8_t vn = *(const half8_t*)&hw[(size_t)sn * D + j8];
#pragma unroll
            for (int j = 0; j < 8; ++j) a[j] = fmaf((float)vc[j], nc, a[j]);
            vc = vn; nc = nn;
        }
#pragma unroll
        for (int j = 0; j < 8; ++j) a[j] = fmaf((float)vc[j], nc, a[j]);
    }
#pragma unroll
    for (int j = 0; j < 8; ++j) a[j] += __shfl_xor(a[j], 16);
    if (half == 0) {
        float dd = dis[node]; float sl = dd * dd;
        half8_t hv = *(const half8_t*)&hw[(size_t)node * D + j8];
        half8_t r;
#pragma unroll
        for (int j = 0; j < 8; ++j) {
            float v = fmaf((float)hv[j], sl, a[j]) + b[j8 + j];
            r[j] = (_Float16)fmaxf(v, 0.f);
        }
        *(half8_t*)&out[(size_t)node * D + j8] = r;
    }
}

// ---------------- fused readout + sim + logits (one block per graph) ----------------
__global__ void k_readout_simlog(const int* __restrict__ batch, const _Float16* __restrict__ h,
                                 const float* __restrict__ pg, const float* __restrict__ lw,
                                 float* __restrict__ out) {
    __shared__ int sh[2];
    __shared__ float red[4][D];
    __shared__ float gs[D];
    __shared__ float sim[N_PROTO];
    int g = blockIdx.x;
    if (threadIdx.x == 0) {
        int lo = 0, hi = N_NODES;
        while (lo < hi) { int m = (lo + hi) >> 1; if (batch[m] < g) lo = m + 1; else hi = m; }
        sh[0] = lo;
        hi = N_NODES;
        while (lo < hi) { int m = (lo + hi) >> 1; if (batch[m] < g + 1) lo = m + 1; else hi = m; }
        sh[1] = lo;
    }
    __syncthreads();
    int s0 = sh[0], s1 = sh[1];
    int col = threadIdx.x & 127;
    int part = threadIdx.x >> 7;          // 0..3
    float sum = 0.f;
    for (int n = s0 + part; n < s1; n += 4) sum += (float)h[(size_t)n * D + col];
    red[part][col] = sum;
    __syncthreads();
    if (part == 0)
        gs[col] = (sum + red[1][col] + red[2][col] + red[3][col])
                  / fmaxf((float)(s1 - s0), 1.0f);
    __syncthreads();
    int t = threadIdx.x;
    if (t < N_PROTO * 8) {                // 8 threads per proto
        int p = t >> 3, sub = t & 7;
        const float* q = pg + (size_t)p * D;
        float d2 = 0.f;
        int j0 = sub * 16;
#pragma unroll
        for (int j = 0; j < 16; ++j) {
            float df = gs[j0 + j] - q[j0 + j];
            d2 = fmaf(df, df, d2);
        }
        d2 += __shfl_xor(d2, 1);
        d2 += __shfl_xor(d2, 2);
        d2 += __shfl_xor(d2, 4);
        if (sub == 0) sim[p] = logf((d2 + 1.0f) / (d2 + EPS_F));
    }
    __syncthreads();
    if (t < N_CLASSES) {
        float s = 0.f;
#pragma unroll
        for (int p = 0; p < N_PROTO; ++p) s = fmaf(sim[p], lw[t * N_PROTO + p], s);
        out[(size_t)g * N_CLASSES + t] = s;
    }
}

extern "C" void kernel_launch(void* const* d_in, const int* in_sizes, int n_in,
                              void* d_out, int out_size, void* d_ws, size_t ws_size,
                              hipStream_t stream) {
    const float* x   = (const float*)d_in[0];
    const int*   ei  = (const int*)d_in[1];
    const int*   bat = (const int*)d_in[2];
    const float* W0  = (const float*)d_in[3];
    const float* b0  = (const float*)d_in[4];
    const float* W1  = (const float*)d_in[5];
    const float* b1  = (const float*)d_in[6];
    const float* W2  = (const float*)d_in[7];
    const float* b2  = (const float*)d_in[8];
    const float* pe  = (const float*)d_in[9];
    const float* lw  = (const float*)d_in[10];
    float* out = (float*)d_out;

    const int* esrc = ei;
    const int* edst = ei + N_EDGES;

    char* wsb = (char*)d_ws;
    _Float16* bufA = (_Float16*)wsb;  wsb += (size_t)N_NODES * D * 2;
    _Float16* bufB = (_Float16*)wsb;  wsb += (size_t)N_NODES * D * 2;
    _Float16* xh   = (_Float16*)wsb;  wsb += (size_t)N_NODES * IN_DIM * 2;
    _Float16* agg0 = (_Float16*)wsb;  wsb += (size_t)N_NODES * IN_DIM * 2;
    _Float16* Bp0  = (_Float16*)wsb;  wsb += (size_t)IN_DIM * D * 2;
    _Float16* Bp1  = (_Float16*)wsb;  wsb += (size_t)D * D * 2;
    _Float16* Bp2  = (_Float16*)wsb;  wsb += (size_t)D * D * 2;
    float* pg      = (float*)wsb;     wsb += (size_t)N_PROTO * D * 4;
    float* dis     = (float*)wsb;     wsb += (size_t)N_NODES * 4;
    float* norm_sorted = (float*)wsb; wsb += (size_t)N_EDGES * 4;
    int*   src_sorted  = (int*)wsb;   wsb += (size_t)N_EDGES * 4;
    int*   indeg   = (int*)wsb;       wsb += (size_t)N_NODES * 4;
    int*   cursor  = (int*)wsb;       wsb += (size_t)N_NODES * 4;   // adjacent to indeg
    int*   row_start = (int*)wsb;     wsb += (size_t)(N_NODES + 1) * 4;
    int*   bsum    = (int*)wsb;       wsb += (size_t)SCAN_B * 4;

    const int TB = 256;
    int e_blocks = (N_EDGES + TB - 1) / TB;
    int s_blocks = (N_NODES + SCAN_B - 1) / SCAN_B;
    int grp_blocks = (N_NODES + 7) / 8;            // 8 nodes per 256-block (32 lanes/node)
    int gemm_blocks = (N_NODES + 63) / 64;

    // ---- CSR build ----
    k_zero<<<(2 * N_NODES + TB - 1) / TB, TB, 0, stream>>>(indeg, 2 * N_NODES);
    k_count_indeg<<<e_blocks, TB, 0, stream>>>(edst, indeg);
    k_scan1<<<s_blocks, SCAN_B, 0, stream>>>(indeg, row_start, bsum, dis, N_NODES);
    k_scan23<<<s_blocks, SCAN_B, 0, stream>>>(row_start, bsum, N_NODES);
    k_fill<<<e_blocks, TB, 0, stream>>>(esrc, edst, row_start, cursor, dis,
                                        src_sorted, norm_sorted);

    // ---- conversions / packs / proto (one launch) ----
    int prep_threads = NC4 + 8192 + 16384 + 16384 + N_PROTO * D;
    k_prep<<<(prep_threads + TB - 1) / TB, TB, 0, stream>>>(x, xh, W0, W1, W2, pe,
                                                            Bp0, Bp1, Bp2, pg);

    // ---- layer 0: aggregate-first (64-dim), then GEMM + bias + relu ----
    k_agg64<<<grp_blocks, TB, 0, stream>>>(row_start, src_sorted, norm_sorted, xh, dis, agg0);
    k_mfma_gemm<IN_DIM, true><<<gemm_blocks, TB, 0, stream>>>(agg0, Bp0, b0, bufB);

    // ---- layer 1 ----
    k_mfma_gemm<D, false><<<gemm_blocks, TB, 0, stream>>>(bufB, Bp1, nullptr, bufA);
    k_gather128<<<grp_blocks, TB, 0, stream>>>(row_start, src_sorted, norm_sorted,
                                               bufA, dis, b1, bufB);
    // ---- layer 2 ----
    k_mfma_gemm<D, false><<<gemm_blocks, TB, 0, stream>>>(bufB, Bp2, nullptr, bufA);
    k_gather128<<<grp_blocks, TB, 0, stream>>>(row_start, src_sorted, norm_sorted,
                                               bufA, dis, b2, bufB);

    // ---- fused readout + sim + logits ----
    k_readout_simlog<<<N_GRAPHS, 512, 0, stream>>>(bat, bufB, pg, lw, out);
}